// Round 15
// baseline (93.596 us; speedup 1.0000x reference)
//
#include <hip/hip_runtime.h>
#include <stdint.h>

#define IN_F 2048
#define OUT_F 2048
#define N_ROWS 8192

// ---- GEMM geometry: 256x256 tile, BK=32, 8 waves (2Mx4N).
// 5-deep LDS ring (160 KiB), TWO K-tiles per barrier window:
// within-window tile-1 reads overlap tile-0 MFMA drain (no barrier between).
#define BM 256
#define BN 256
#define BK 32
#define NT (IN_F / BK)             // 64 K-tiles, 32 windows
#define TM_TILES (N_ROWS / BM)     // 32
#define TN_TILES (OUT_F / BN)      // 8
#define NWG (TM_TILES * TN_TILES)  // 256 == #CUs
#define TILE_SHORTS (BM * BK)      // 8192 shorts = 16 KiB per (tile,kstep)
#define BUF_SHORTS (2 * TILE_SHORTS)  // A+B = 32 KiB per ring slot

typedef __bf16 bf16x8 __attribute__((ext_vector_type(8)));
typedef float f32x4 __attribute__((ext_vector_type(4)));
typedef unsigned short ushortx8 __attribute__((ext_vector_type(8)));

__device__ __forceinline__ unsigned short f2bf(float f) {
  unsigned u = __builtin_bit_cast(unsigned, f);
  u += 0x7FFFu + ((u >> 16) & 1u);
  return (unsigned short)(u >> 16);
}

__device__ __forceinline__ void async16(void* lds, const void* g) {
  __builtin_amdgcn_global_load_lds(
      (const __attribute__((address_space(1))) void*)(uintptr_t)g,
      (__attribute__((address_space(3))) void*)(uint32_t)(uintptr_t)lds,
      16, 0, 0);
}

__device__ __forceinline__ bf16x8 ld8(const unsigned short* p) {
  return __builtin_bit_cast(bf16x8, *reinterpret_cast<const ushortx8*>(p));
}

// ---- prep: pre-tiled, pre-swizzled staging images (identical to r11/r14).
// Chunk t in [0,1024) of tile (X*64+T): row r=t>>2, slot s=t&3 holds
// k-group ga = s ^ ((r>>1)&3)  (same swizzle the GEMM reads with).
__global__ __launch_bounds__(256) void k_prep(const float* __restrict__ A,
                                              unsigned short* __restrict__ AbT,
                                              const float* __restrict__ W,
                                              unsigned short* __restrict__ BtT) {
  const int bid = blockIdx.x;
  if (bid < 8192) {
    const int tile = bid >> 2;                       // R*64 + T
    const int t = ((bid & 3) << 8) + threadIdx.x;    // chunk 0..1023
    const int r = t >> 2;
    const int ga = (t & 3) ^ ((r >> 1) & 3);
    const int R = tile >> 6, T = tile & 63;
    const float* src = A + (size_t)(R * 256 + r) * IN_F + T * 32 + ga * 8;
    const float4 v0 = *reinterpret_cast<const float4*>(src);
    const float4 v1 = *reinterpret_cast<const float4*>(src + 4);
    ushortx8 o;
    o[0] = f2bf(v0.x); o[1] = f2bf(v0.y); o[2] = f2bf(v0.z); o[3] = f2bf(v0.w);
    o[4] = f2bf(v1.x); o[5] = f2bf(v1.y); o[6] = f2bf(v1.z); o[7] = f2bf(v1.w);
    *reinterpret_cast<ushortx8*>(AbT + (size_t)tile * 8192 + t * 8) = o;
  } else {
    const int bb = bid - 8192;                       // 0..2047
    const int tile = bb >> 2;                        // Ct*64 + T, 0..511
    const int t = ((bb & 3) << 8) + threadIdx.x;
    const int r = t >> 2;
    const int ga = (t & 3) ^ ((r >> 1) & 3);
    const int Ct = tile >> 6, T = tile & 63;
    const int b = Ct * 256 + r;
    const int c = b & 3, v = b >> 2;
    const int a0 = T * 32 + ga * 8;
    ushortx8 o;
#pragma unroll
    for (int e = 0; e < 8; ++e) {
      const int a = a0 + e;
      const int q = a & 3, u = a >> 2;
      float w = W[(size_t)u * OUT_F + ((q ^ c) << 9) + v];
      if ((0x284E >> ((q << 2) | c)) & 1) w = -w;
      o[e] = f2bf(w);
    }
    *reinterpret_cast<ushortx8*>(BtT + (size_t)tile * 8192 + t * 8) = o;
  }
}

// ---- main GEMM: C = A(bf16) @ Ht^T + bias ----
__global__ __launch_bounds__(512, 2) void k_gemm(const unsigned short* __restrict__ AbT,
                                                 const unsigned short* __restrict__ BtT,
                                                 const float* __restrict__ bias,
                                                 float* __restrict__ C) {
  __shared__ __align__(16) unsigned short lds[5 * BUF_SHORTS];  // 160 KiB ring

  const int tid = threadIdx.x;
  const int lane = tid & 63;
  const int w = tid >> 6;   // wave 0..7
  const int wm = w >> 2;    // 0..1 -> rows wm*128..+128
  const int wn = w & 3;     // 0..3 -> cols wn*64..+64
  const int fr = lane & 15;
  const int g = lane >> 4;  // k-group 0..3 (8 bf16 each)

  // XCD-bijective swizzle: 256 wgs, 32 contiguous tiles per XCD
  const int wg = blockIdx.x;
  const int swz = (wg & 7) * (NWG >> 3) + (wg >> 3);
  const int tm = swz >> 3;
  const int tn = swz & 7;
  const int row0 = tm * BM, col0 = tn * BN;

  // ---- staging: pre-tiled images -> fully linear DMA (2x1KB A + 2x1KB B/wave)
  const unsigned short* baseA = AbT + (size_t)tm * 64 * 8192;
  const unsigned short* baseB = BtT + (size_t)tn * 64 * 8192;
  const int tOff0 = (w * 128 + lane) * 8;        // shorts
  const int tOff1 = (w * 128 + 64 + lane) * 8;

#define STAGE(T, BUF)                                              \
  do {                                                             \
    unsigned short* base_ = &lds[(BUF) * BUF_SHORTS];              \
    const unsigned short* sa_ = baseA + (size_t)(T) * 8192;        \
    const unsigned short* sb_ = baseB + (size_t)(T) * 8192;        \
    async16(base_ + tOff0, sa_ + tOff0);                           \
    async16(base_ + tOff1, sa_ + tOff1);                           \
    async16(base_ + TILE_SHORTS + tOff0, sb_ + tOff0);             \
    async16(base_ + TILE_SHORTS + tOff1, sb_ + tOff1);             \
  } while (0)

  // ---- fragment read offsets (shorts), read swizzle = baked image swizzle
  int offA[8], offB[4];
#pragma unroll
  for (int m = 0; m < 8; ++m) {
    const int r = wm * 128 + m * 16 + fr;
    offA[m] = r * BK + ((g ^ ((r >> 1) & 3)) << 3);
  }
#pragma unroll
  for (int n = 0; n < 4; ++n) {
    const int r = wn * 64 + n * 16 + fr;
    offB[n] = TILE_SHORTS + r * BK + ((g ^ ((r >> 1) & 3)) << 3);
  }

  f32x4 acc[8][4] = {};

#define MFMA_(a_, b_, c_) __builtin_amdgcn_mfma_f32_16x16x32_bf16(a_, b_, c_, 0, 0, 0)

  // Window (tiles T, T+1 from ring slots B0,B1): vmcnt(N) [retires exactly
  // tiles T,T+1; stages ≥2 windows old stay in flight] -> barrier [all waves
  // done with the ring slots being overwritten this window] -> reads t0 ->
  // stages (slots last read at window w-1) -> reads t1 -> MFMA t0 (counted
  // lgkm: t1 reads still outstanding -> t1 reads drain under t0 MFMA) ->
  // MFMA t1. No barrier between tiles: cross-tile overlap within the wave.
#define WINDOW(T, B0, B1, S0, S1, VMSTR, NS)                                  \
  do {                                                                        \
    asm volatile("s_waitcnt vmcnt(" VMSTR ")" ::: "memory");                  \
    __builtin_amdgcn_s_barrier();                                             \
    __builtin_amdgcn_sched_barrier(0);                                        \
    const unsigned short* p0_ = &lds[(B0) * BUF_SHORTS];                      \
    const unsigned short* p1_ = &lds[(B1) * BUF_SHORTS];                      \
    bf16x8 bg0[4], bg1[4], af0[8], af1[8];                                    \
    _Pragma("unroll") for (int n = 0; n < 4; ++n) bg0[n] = ld8(p0_ + offB[n]);\
    _Pragma("unroll") for (int m = 0; m < 8; ++m) af0[m] = ld8(p0_ + offA[m]);\
    if ((NS) >= 1) STAGE((T) + 3, S0);                                        \
    if ((NS) >= 2) STAGE((T) + 4, S1);                                        \
    _Pragma("unroll") for (int n = 0; n < 4; ++n) bg1[n] = ld8(p1_ + offB[n]);\
    _Pragma("unroll") for (int m = 0; m < 8; ++m) af1[m] = ld8(p1_ + offA[m]);\
    __builtin_amdgcn_s_setprio(1);                                            \
    _Pragma("unroll") for (int m = 0; m < 8; ++m)                             \
      _Pragma("unroll") for (int n = 0; n < 4; ++n)                           \
        acc[m][n] = MFMA_(af0[m], bg0[n], acc[m][n]);                         \
    _Pragma("unroll") for (int m = 0; m < 8; ++m)                             \
      _Pragma("unroll") for (int n = 0; n < 4; ++n)                           \
        acc[m][n] = MFMA_(af1[m], bg1[n], acc[m][n]);                         \
    __builtin_amdgcn_s_setprio(0);                                            \
  } while (0)

  // prologue: tiles 0,1,2 into ring slots 0,1,2 (12 loads/wave in flight)
  STAGE(0, 0);
  STAGE(1, 1);
  STAGE(2, 2);

  // 30 steady windows (3 groups of 5; mod-5 pattern repeats every 10 tiles)
#pragma unroll 1
  for (int tb = 0; tb < NT - 4; tb += 10) {
    WINDOW(tb + 0, 0, 1, 3, 4, "4", 2);
    WINDOW(tb + 2, 2, 3, 0, 1, "4", 2);
    WINDOW(tb + 4, 4, 0, 2, 3, "4", 2);
    WINDOW(tb + 6, 1, 2, 4, 0, "4", 2);
    WINDOW(tb + 8, 3, 4, 1, 2, "4", 2);
  }
  // tail: window 30 stages only tile 63; window 31 drains
  WINDOW(NT - 4, 0, 1, 3, 3, "4", 1);
  WINDOW(NT - 2, 2, 3, 0, 0, "0", 0);

#undef WINDOW
#undef STAGE

  // ---- epilogue: C/D layout col=lane&15, row=(lane>>4)*4+reg ----
  const int g4 = g << 2;
  float bv[4];
#pragma unroll
  for (int n = 0; n < 4; ++n) bv[n] = bias[col0 + wn * 64 + n * 16 + fr];
#pragma unroll
  for (int m = 0; m < 8; ++m) {
#pragma unroll
    for (int e = 0; e < 4; ++e) {
      const int row = row0 + wm * 128 + m * 16 + g4 + e;
      float* cp = C + (size_t)row * OUT_F + col0 + wn * 64 + fr;
#pragma unroll
      for (int n = 0; n < 4; ++n) cp[n * 16] = acc[m][n][e] + bv[n];
    }
  }
}

// ---- fallback if workspace too small: naive fp32 ----
__global__ __launch_bounds__(256) void k_naive(const float* __restrict__ A,
                                               const float* __restrict__ W,
                                               const float* __restrict__ bias,
                                               float* __restrict__ C) {
  const int idx = blockIdx.x * 256 + threadIdx.x;
  const int m = idx >> 11;
  const int b = idx & (OUT_F - 1);
  const int c = b & 3, v = b >> 2;
  float acc = 0.f;
  const float* arow = A + (size_t)m * IN_F;
  for (int a = 0; a < IN_F; ++a) {
    const int q = a & 3, u = a >> 2;
    float h = W[(size_t)u * OUT_F + ((q ^ c) << 9) + v];
    if ((0x284E >> ((q << 2) | c)) & 1) h = -h;
    acc += arow[a] * h;
  }
  C[idx] = acc + bias[b];
}

extern "C" void kernel_launch(void* const* d_in, const int* in_sizes, int n_in,
                              void* d_out, int out_size, void* d_ws, size_t ws_size,
                              hipStream_t stream) {
  (void)in_sizes; (void)n_in; (void)out_size;
  const float* inp  = (const float*)d_in[0];
  const float* w    = (const float*)d_in[1];
  const float* bias = (const float*)d_in[2];
  float* out = (float*)d_out;

  const size_t needA = (size_t)N_ROWS * IN_F * sizeof(unsigned short);  // 32 MiB
  const size_t needB = (size_t)IN_F * OUT_F * sizeof(unsigned short);   //  8 MiB
  if (ws_size < needA + needB) {
    k_naive<<<(N_ROWS * OUT_F) / 256, 256, 0, stream>>>(inp, w, bias, out);
    return;
  }

  unsigned short* AbT = (unsigned short*)d_ws;
  unsigned short* BtT = AbT + (size_t)N_ROWS * IN_F;

  k_prep<<<8192 + 2048, 256, 0, stream>>>(inp, AbT, w, BtT);
  k_gemm<<<NWG, 512, 0, stream>>>(AbT, BtT, bias, out);
}

// Round 16
// 90.598 us; speedup vs baseline: 1.0331x; 1.0331x over previous
//
#include <hip/hip_runtime.h>
#include <stdint.h>

#define IN_F 2048
#define OUT_F 2048
#define N_ROWS 8192

// ---- GEMM geometry: 256x256 tile, BK=32, 8 waves (2Mx4N), 5-deep LDS ring.
// One-step-ahead register fragments + sched_group_barrier 3:1 MFMA/ds_read
// interleave: reads(T+1) issue inside the MFMA(T) stream (co-issue).
#define BM 256
#define BN 256
#define BK 32
#define NT (IN_F / BK)             // 64 K-steps
#define TM_TILES (N_ROWS / BM)     // 32
#define TN_TILES (OUT_F / BN)      // 8
#define NWG (TM_TILES * TN_TILES)  // 256 == #CUs
#define TILE_SHORTS (BM * BK)      // 8192 shorts = 16 KiB per (tile,kstep)
#define BUF_SHORTS (2 * TILE_SHORTS)  // A+B = 32 KiB per ring slot

typedef __bf16 bf16x8 __attribute__((ext_vector_type(8)));
typedef float f32x4 __attribute__((ext_vector_type(4)));
typedef unsigned short ushortx8 __attribute__((ext_vector_type(8)));

__device__ __forceinline__ unsigned short f2bf(float f) {
  unsigned u = __builtin_bit_cast(unsigned, f);
  u += 0x7FFFu + ((u >> 16) & 1u);
  return (unsigned short)(u >> 16);
}

__device__ __forceinline__ void async16(void* lds, const void* g) {
  __builtin_amdgcn_global_load_lds(
      (const __attribute__((address_space(1))) void*)(uintptr_t)g,
      (__attribute__((address_space(3))) void*)(uint32_t)(uintptr_t)lds,
      16, 0, 0);
}

__device__ __forceinline__ bf16x8 ld8(const unsigned short* p) {
  return __builtin_bit_cast(bf16x8, *reinterpret_cast<const ushortx8*>(p));
}

// ---- prep: pre-tiled, pre-swizzled staging images (identical to r11/r14).
// Chunk t in [0,1024) of tile (X*64+T): row r=t>>2, slot s=t&3 holds
// k-group ga = s ^ ((r>>1)&3)  (same swizzle the GEMM reads with).
__global__ __launch_bounds__(256) void k_prep(const float* __restrict__ A,
                                              unsigned short* __restrict__ AbT,
                                              const float* __restrict__ W,
                                              unsigned short* __restrict__ BtT) {
  const int bid = blockIdx.x;
  if (bid < 8192) {
    const int tile = bid >> 2;                       // R*64 + T
    const int t = ((bid & 3) << 8) + threadIdx.x;    // chunk 0..1023
    const int r = t >> 2;
    const int ga = (t & 3) ^ ((r >> 1) & 3);
    const int R = tile >> 6, T = tile & 63;
    const float* src = A + (size_t)(R * 256 + r) * IN_F + T * 32 + ga * 8;
    const float4 v0 = *reinterpret_cast<const float4*>(src);
    const float4 v1 = *reinterpret_cast<const float4*>(src + 4);
    ushortx8 o;
    o[0] = f2bf(v0.x); o[1] = f2bf(v0.y); o[2] = f2bf(v0.z); o[3] = f2bf(v0.w);
    o[4] = f2bf(v1.x); o[5] = f2bf(v1.y); o[6] = f2bf(v1.z); o[7] = f2bf(v1.w);
    *reinterpret_cast<ushortx8*>(AbT + (size_t)tile * 8192 + t * 8) = o;
  } else {
    const int bb = bid - 8192;                       // 0..2047
    const int tile = bb >> 2;                        // Ct*64 + T, 0..511
    const int t = ((bb & 3) << 8) + threadIdx.x;
    const int r = t >> 2;
    const int ga = (t & 3) ^ ((r >> 1) & 3);
    const int Ct = tile >> 6, T = tile & 63;
    const int b = Ct * 256 + r;
    const int c = b & 3, v = b >> 2;
    const int a0 = T * 32 + ga * 8;
    ushortx8 o;
#pragma unroll
    for (int e = 0; e < 8; ++e) {
      const int a = a0 + e;
      const int q = a & 3, u = a >> 2;
      float w = W[(size_t)u * OUT_F + ((q ^ c) << 9) + v];
      if ((0x284E >> ((q << 2) | c)) & 1) w = -w;
      o[e] = f2bf(w);
    }
    *reinterpret_cast<ushortx8*>(BtT + (size_t)tile * 8192 + t * 8) = o;
  }
}

// ---- main GEMM: C = A(bf16) @ Ht^T + bias ----
__global__ __launch_bounds__(512, 2) void k_gemm(const unsigned short* __restrict__ AbT,
                                                 const unsigned short* __restrict__ BtT,
                                                 const float* __restrict__ bias,
                                                 float* __restrict__ C) {
  __shared__ __align__(16) unsigned short lds[5 * BUF_SHORTS];  // 160 KiB ring

  const int tid = threadIdx.x;
  const int lane = tid & 63;
  const int w = tid >> 6;   // wave 0..7
  const int wm = w >> 2;    // 0..1 -> rows wm*128..+128
  const int wn = w & 3;     // 0..3 -> cols wn*64..+64
  const int fr = lane & 15;
  const int g = lane >> 4;  // k-group 0..3 (8 bf16 each)

  // XCD-bijective swizzle: 256 wgs, 32 contiguous tiles per XCD
  const int wg = blockIdx.x;
  const int swz = (wg & 7) * (NWG >> 3) + (wg >> 3);
  const int tm = swz >> 3;
  const int tn = swz & 7;
  const int row0 = tm * BM, col0 = tn * BN;

  // ---- staging: pre-tiled images -> fully linear DMA (2x1KB A + 2x1KB B/wave)
  const unsigned short* baseA = AbT + (size_t)tm * 64 * 8192;
  const unsigned short* baseB = BtT + (size_t)tn * 64 * 8192;
  const int tOff0 = (w * 128 + lane) * 8;        // shorts
  const int tOff1 = (w * 128 + 64 + lane) * 8;

#define STAGE(T, BUF)                                              \
  do {                                                             \
    unsigned short* base_ = &lds[(BUF) * BUF_SHORTS];              \
    const unsigned short* sa_ = baseA + (size_t)(T) * 8192;        \
    const unsigned short* sb_ = baseB + (size_t)(T) * 8192;        \
    async16(base_ + tOff0, sa_ + tOff0);                           \
    async16(base_ + tOff1, sa_ + tOff1);                           \
    async16(base_ + TILE_SHORTS + tOff0, sb_ + tOff0);             \
    async16(base_ + TILE_SHORTS + tOff1, sb_ + tOff1);             \
  } while (0)

  // ---- fragment read offsets (shorts), read swizzle = baked image swizzle
  int offA[8], offB[4];
#pragma unroll
  for (int m = 0; m < 8; ++m) {
    const int r = wm * 128 + m * 16 + fr;
    offA[m] = r * BK + ((g ^ ((r >> 1) & 3)) << 3);
  }
#pragma unroll
  for (int n = 0; n < 4; ++n) {
    const int r = wn * 64 + n * 16 + fr;
    offB[n] = TILE_SHORTS + r * BK + ((g ^ ((r >> 1) & 3)) << 3);
  }

  f32x4 acc[8][4] = {};
  bf16x8 afE[8], bgE[4], afO[8], bgO[4];  // one-step-ahead parity sets

#define MFMA_(a_, b_, c_) __builtin_amdgcn_mfma_f32_16x16x32_bf16(a_, b_, c_, 0, 0, 0)

  // Step T: vmcnt(N) [every wave: stage(T+1) retired] -> barrier [slot(T+1)
  // complete block-wide; reads of slot being staged drained 2 steps ago] ->
  // region { stage(T+3); reads(T+1)->NXT regs; MFMA(T) on CUR regs } with
  // sched_group_barrier forcing VMEMx4, then 12x(2 MFMA + 1 ds_read), then
  // 8 MFMA: reads issue inside the MFMA stream (co-issue on separate pipes).
#define STEP(T, SN, SS, AFC, BGC, AFN, BGN, VMSTR, DOSTAGE, DOREAD)            \
  do {                                                                         \
    asm volatile("s_waitcnt vmcnt(" VMSTR ")" ::: "memory");                   \
    __builtin_amdgcn_s_barrier();                                              \
    __builtin_amdgcn_sched_barrier(0);                                         \
    if (DOSTAGE) STAGE((T) + 3, SS);                                           \
    if (DOREAD) {                                                              \
      const unsigned short* pn_ = &lds[(SN) * BUF_SHORTS];                     \
      _Pragma("unroll") for (int n = 0; n < 4; ++n)                            \
          BGN[n] = ld8(pn_ + offB[n]);                                         \
      _Pragma("unroll") for (int m = 0; m < 8; ++m)                            \
          AFN[m] = ld8(pn_ + offA[m]);                                         \
    }                                                                          \
    __builtin_amdgcn_s_setprio(1);                                             \
    _Pragma("unroll") for (int m = 0; m < 8; ++m)                              \
      _Pragma("unroll") for (int n = 0; n < 4; ++n)                            \
        acc[m][n] = MFMA_(AFC[m], BGC[n], acc[m][n]);                          \
    __builtin_amdgcn_s_setprio(0);                                             \
    if (DOSTAGE) __builtin_amdgcn_sched_group_barrier(0x010, 4, 0);            \
    if (DOREAD) {                                                              \
      _Pragma("unroll") for (int i_ = 0; i_ < 12; ++i_) {                      \
        __builtin_amdgcn_sched_group_barrier(0x008, 2, 0);                     \
        __builtin_amdgcn_sched_group_barrier(0x100, 1, 0);                     \
      }                                                                        \
      __builtin_amdgcn_sched_group_barrier(0x008, 8, 0);                       \
    }                                                                          \
    __builtin_amdgcn_sched_barrier(0);                                         \
  } while (0)

  // ---- prologue: tiles 0,1,2 -> slots 0,1,2; tile 0 frags -> E set ----
  STAGE(0, 0);
  STAGE(1, 1);
  STAGE(2, 2);
  asm volatile("s_waitcnt vmcnt(8)" ::: "memory");  // stage(0) retired
  __builtin_amdgcn_s_barrier();
  {
    const unsigned short* p0_ = &lds[0];
#pragma unroll
    for (int n = 0; n < 4; ++n) bgE[n] = ld8(p0_ + offB[n]);
#pragma unroll
    for (int m = 0; m < 8; ++m) afE[m] = ld8(p0_ + offA[m]);
  }

  // steady: T=0..59, 10-step unrolled groups (slot pattern period 5 x parity 2)
#pragma unroll 1
  for (int t0 = 0; t0 < NT - 4; t0 += 10) {
    STEP(t0 + 0, 1, 3, afE, bgE, afO, bgO, "4", 1, 1);
    STEP(t0 + 1, 2, 4, afO, bgO, afE, bgE, "4", 1, 1);
    STEP(t0 + 2, 3, 0, afE, bgE, afO, bgO, "4", 1, 1);
    STEP(t0 + 3, 4, 1, afO, bgO, afE, bgE, "4", 1, 1);
    STEP(t0 + 4, 0, 2, afE, bgE, afO, bgO, "4", 1, 1);
    STEP(t0 + 5, 1, 3, afO, bgO, afE, bgE, "4", 1, 1);
    STEP(t0 + 6, 2, 4, afE, bgE, afO, bgO, "4", 1, 1);
    STEP(t0 + 7, 3, 0, afO, bgO, afE, bgE, "4", 1, 1);
    STEP(t0 + 8, 4, 1, afE, bgE, afO, bgO, "4", 1, 1);
    STEP(t0 + 9, 0, 2, afO, bgO, afE, bgE, "4", 1, 1);
  }
  // tail: T=60 (stage 63 -> slot 3), 61, 62 (vm0 for tile 63), 63 (drain)
  STEP(NT - 4, 1, 3, afE, bgE, afO, bgO, "4", 1, 1);
  STEP(NT - 3, 2, 0, afO, bgO, afE, bgE, "4", 0, 1);
  STEP(NT - 2, 3, 0, afE, bgE, afO, bgO, "0", 0, 1);
  STEP(NT - 1, 4, 0, afO, bgO, afE, bgE, "0", 0, 0);

#undef STEP
#undef STAGE

  // ---- epilogue: C/D layout col=lane&15, row=(lane>>4)*4+reg ----
  const int g4 = g << 2;
  float bv[4];
#pragma unroll
  for (int n = 0; n < 4; ++n) bv[n] = bias[col0 + wn * 64 + n * 16 + fr];
#pragma unroll
  for (int m = 0; m < 8; ++m) {
#pragma unroll
    for (int e = 0; e < 4; ++e) {
      const int row = row0 + wm * 128 + m * 16 + g4 + e;
      float* cp = C + (size_t)row * OUT_F + col0 + wn * 64 + fr;
#pragma unroll
      for (int n = 0; n < 4; ++n) cp[n * 16] = acc[m][n][e] + bv[n];
    }
  }
}

// ---- fallback if workspace too small: naive fp32 ----
__global__ __launch_bounds__(256) void k_naive(const float* __restrict__ A,
                                               const float* __restrict__ W,
                                               const float* __restrict__ bias,
                                               float* __restrict__ C) {
  const int idx = blockIdx.x * 256 + threadIdx.x;
  const int m = idx >> 11;
  const int b = idx & (OUT_F - 1);
  const int c = b & 3, v = b >> 2;
  float acc = 0.f;
  const float* arow = A + (size_t)m * IN_F;
  for (int a = 0; a < IN_F; ++a) {
    const int q = a & 3, u = a >> 2;
    float h = W[(size_t)u * OUT_F + ((q ^ c) << 9) + v];
    if ((0x284E >> ((q << 2) | c)) & 1) h = -h;
    acc += arow[a] * h;
  }
  C[idx] = acc + bias[b];
}

extern "C" void kernel_launch(void* const* d_in, const int* in_sizes, int n_in,
                              void* d_out, int out_size, void* d_ws, size_t ws_size,
                              hipStream_t stream) {
  (void)in_sizes; (void)n_in; (void)out_size;
  const float* inp  = (const float*)d_in[0];
  const float* w    = (const float*)d_in[1];
  const float* bias = (const float*)d_in[2];
  float* out = (float*)d_out;

  const size_t needA = (size_t)N_ROWS * IN_F * sizeof(unsigned short);  // 32 MiB
  const size_t needB = (size_t)IN_F * OUT_F * sizeof(unsigned short);   //  8 MiB
  if (ws_size < needA + needB) {
    k_naive<<<(N_ROWS * OUT_F) / 256, 256, 0, stream>>>(inp, w, bias, out);
    return;
  }

  unsigned short* AbT = (unsigned short*)d_ws;
  unsigned short* BtT = AbT + (size_t)N_ROWS * IN_F;

  k_prep<<<8192 + 2048, 256, 0, stream>>>(inp, AbT, w, BtT);
  k_gemm<<<NWG, 512, 0, stream>>>(AbT, BtT, bias, out);
}